// Round 5
// baseline (537.562 us; speedup 1.0000x reference)
//
#include <hip/hip_runtime.h>
#include <hip/hip_cooperative_groups.h>
#include <hip/hip_fp16.h>
#include <math.h>

#define N_NODES 50000
#define N_EDGES 1600000
#define D_INF   128
#define D_HID   64
#define BN_EPS  1e-5f
#define NBINS   391      // fine bins, 128 nodes each (bin = dst >> 7)
#define BINCAP  4608     // per-bin cap (mean 4092, +8 sigma)
#define EPB     6250     // edges per binA block (256 blocks x 6250 = E)
#define GEMM1B  3125     // gemm1 blocks inside k_pre
#define NPAIR   3125     // gather block-pairs (16 nodes each)
#define NCOPY   64       // BN stat accumulator copies (atomic spread)

// ============ fused k_pre: blocks 0..255 binA | 256..3380 gemm1 ============
// R3-verbatim (REVERT of R4's direct-CSR: random 4B scatter across a
// 19.2MB multi-XCD-shared array = 8x write amplification, WRITE_SIZE
// 36->153MB measured). binA's binned writes stay XCD-line-dense.
struct SmGemm { float sw[D_INF * D_HID]; float sx[16 * D_INF]; };  // 40 KB
struct SmBin  { int hcnt[NBINS]; int hbase[NBINS]; };              // 3.1 KB
union SmPre { SmGemm g; SmBin a; };

__global__ __launch_bounds__(256) void k_pre(const float* __restrict__ wsc,
                                             const float* __restrict__ wfc,
                                             const int*   __restrict__ ei,
                                             const float* __restrict__ alpha,
                                             int* __restrict__ bin_cur,
                                             unsigned long long* __restrict__ binned,
                                             const float* __restrict__ x,
                                             const float* __restrict__ W,
                                             __half* __restrict__ ha,
                                             __half* __restrict__ hb) {
    __shared__ SmPre sm;
    int t = threadIdx.x;
    if (blockIdx.x < 256) {
        int e0 = blockIdx.x * EPB;
        for (int b = t; b < NBINS; b += 256) sm.a.hcnt[b] = 0;
        __syncthreads();
        for (int i = t; i < EPB; i += 256)
            atomicAdd(&sm.a.hcnt[ei[N_EDGES + e0 + i] >> 7], 1);
        __syncthreads();
        for (int b = t; b < NBINS; b += 256) {
            int c = sm.a.hcnt[b];
            sm.a.hbase[b] = c ? atomicAdd(&bin_cur[b], c) : 0;
            sm.a.hcnt[b] = 0;
        }
        __syncthreads();
        float a = 1.0f / (1.0f + expf(-alpha[0]));
        for (int i = t; i < EPB; i += 256) {
            int e = e0 + i;
            int s = ei[e], d = ei[N_EDGES + e];
            float wm = fmaf(a, wsc[e] - wfc[e], wfc[e]);   // a*wsc+(1-a)*wfc
            int bin = d >> 7;
            int slot = atomicAdd(&sm.a.hcnt[bin], 1);
            int gpos = sm.a.hbase[bin] + slot;
            if (gpos < BINCAP) {
                unsigned long long ent =
                    ((unsigned long long)__float_as_uint(wm) << 32)
                    | (unsigned int)(s | ((d & 127) << 16));
                binned[(size_t)bin * BINCAP + gpos] = ent;
            }
        }
    } else {
        int row0 = (blockIdx.x - 256) * 16;
#pragma unroll
        for (int j = 0; j < 32; ++j) sm.g.sw[t + j * 256] = W[t + j * 256];
#pragma unroll
        for (int j = 0; j < 8; ++j) {
            int i = t + j * 256;
            int r = i >> 7, k = i & 127;
            sm.g.sx[i] = x[(row0 + r) * D_INF + k];
        }
        __syncthreads();
        int c = t & 63, rg = (t >> 6) * 4;
        float a0 = 0, a1 = 0, a2 = 0, a3 = 0;
#pragma unroll 4
        for (int k = 0; k < D_INF; ++k) {
            float w = sm.g.sw[k * D_HID + c];
            a0 = fmaf(sm.g.sx[(rg + 0) * D_INF + k], w, a0);
            a1 = fmaf(sm.g.sx[(rg + 1) * D_INF + k], w, a1);
            a2 = fmaf(sm.g.sx[(rg + 2) * D_INF + k], w, a2);
            a3 = fmaf(sm.g.sx[(rg + 3) * D_INF + k], w, a3);
        }
        __half* tbl = (c < 32) ? ha : hb;
        int cc = c & 31;
        tbl[(row0 + rg + 0) * 32 + cc] = __float2half_rn(a0);
        tbl[(row0 + rg + 1) * 32 + cc] = __float2half_rn(a1);
        tbl[(row0 + rg + 2) * 32 + cc] = __float2half_rn(a2);
        tbl[(row0 + rg + 3) * 32 + cc] = __float2half_rn(a3);
    }
}

// ===================== shared-memory unions for the megakernel =============
struct SmBinB {
    unsigned long long stage[BINCAP];   // 36.9 KB
    int   ncnt[128];
    float ndeg[128];
    int   sscan[128];
    float sdinv[128];
    int   lb[128];
};                                       // 39.4 KB total
struct SmGath { float s1[512]; float s2[512]; };                   // 4 KB
struct SmG2   { float sw[D_HID * D_HID]; float sx[16 * D_HID];
                float sc[D_HID]; float sh[D_HID]; };               // 20.5 KB
union SmMega { SmBinB b; SmGath s; SmG2 g; };                      // 39.4 KB

// ============ binB body (R3-verbatim + trailing sync) ======================
__device__ __forceinline__ void binB_body(int bin, int t, SmBinB& s,
        const int* bin_cur, const unsigned long long* binned,
        int2* row_se, float* dinv, __half* ha, __half* hb, unsigned int* csr) {
    if (t < 128) { s.ncnt[t] = 0; s.ndeg[t] = 0.0f; }
    int cnt = min(bin_cur[bin], BINCAP);
    const unsigned long long* mybin = binned + (size_t)bin * BINCAP;
    for (int i = t; i < cnt; i += 512) s.stage[i] = mybin[i];
    __syncthreads();
    for (int i = t; i < cnt; i += 512) {
        unsigned long long ent = s.stage[i];
        unsigned int lo = (unsigned int)ent;
        int nl = (lo >> 16) & 127;
        float wm = __uint_as_float((unsigned int)(ent >> 32));
        atomicAdd(&s.ncnt[nl], 1);
        atomicAdd(&s.ndeg[nl], wm);
    }
    __syncthreads();
    int node0 = bin << 7;
    int nnodes = min(128, N_NODES - node0);
    if (t < 128) {
        float dv = rsqrtf(1.0f + s.ndeg[t]);   // +1 self loop
        s.sdinv[t] = dv;
        if (t < nnodes) dinv[node0 + t] = dv;
        s.sscan[t] = s.ncnt[t];
    }
    __syncthreads();
    for (int off = 1; off < 128; off <<= 1) {
        int u = (t >= off && t < 128) ? s.sscan[t - off] : 0;
        __syncthreads();
        if (t < 128) s.sscan[t] += u;
        __syncthreads();
    }
    if (t < nnodes) {
        int st = bin * BINCAP + s.sscan[t] - s.ncnt[t];
        row_se[node0 + t] = make_int2(st, st + s.ncnt[t]);
        s.lb[t] = st;
    }
    __syncthreads();
    int nh = nnodes * 32;
    for (int i = t; i < nh; i += 512) {
        int n = i >> 5, c = i & 31;
        float dv = s.sdinv[n];
        int idx = (node0 + n) * 32 + c;
        ha[idx] = __float2half_rn(__half2float(ha[idx]) * dv);
        hb[idx] = __float2half_rn(__half2float(hb[idx]) * dv);
    }
    if (t < 128) s.ncnt[t] = 0;   // reuse as fill cursor
    __syncthreads();
    for (int i = t; i < cnt; i += 512) {
        unsigned long long ent = s.stage[i];
        unsigned int lo = (unsigned int)ent;
        int nl  = (lo >> 16) & 127;
        int src = lo & 0xFFFFu;
        float wm = __uint_as_float((unsigned int)(ent >> 32));
        int slot = atomicAdd(&s.ncnt[nl], 1);
        unsigned short wh = __half_as_ushort(__float2half_rn(wm));
        csr[s.lb[nl] + slot] = (unsigned int)src | ((unsigned int)wh << 16);
    }
    __syncthreads();   // stage/ncnt reuse across persistent iterations
}

__device__ inline float hdec(unsigned int u) {
    return __half2float(__ushort_as_half((unsigned short)(u >> 16)));
}

// ============ gather body (R3-verbatim v2 + trailing sync) =================
// 16B/lane table reads (R3-validated 123->38us): cq=ln&3 picks a float4 of
// the 64B row; sg=ln>>2 picks the edge. BN stats via NCOPY-spread atomics.
__device__ __forceinline__ void gather_body(int vb, int t, SmGath& sm,
        const __half* ha, const __half* hb, const unsigned int* csr,
        const int2* row_se, const float* dinv, const float* bias,
        float* out, float* stat) {
    int half = vb & 1;
    const float4* h4 = (const float4*)(half ? hb : ha);
    int node = (vb >> 1) * 16 + (t >> 5);
    int ln = t & 31;
    int sg = ln >> 2;
    int cq = ln & 3;
    int2 se = row_se[node];
    float dd = dinv[node];
    float acc[8];
    if (sg == 0) {        // self term (pre-scaled by dinv), added once
        float4 sv = h4[node * 4 + cq];
        const __half2* p = reinterpret_cast<const __half2*>(&sv);
#pragma unroll
        for (int i = 0; i < 4; ++i) {
            float2 f = __half22float2(p[i]);
            acc[2 * i] = f.x; acc[2 * i + 1] = f.y;
        }
    } else {
#pragma unroll
        for (int i = 0; i < 8; ++i) acc[i] = 0.0f;
    }
    for (int b = se.x; b < se.y; b += 32) {
        int c0 = min(32, se.y - b);
        int cm = c0 - 1;
        unsigned int my = (ln < c0) ? csr[b + ln] : 0u;
        unsigned int u0 = __shfl(my, min(sg,      cm), 32);
        unsigned int u1 = __shfl(my, min(sg + 8,  cm), 32);
        unsigned int u2 = __shfl(my, min(sg + 16, cm), 32);
        unsigned int u3 = __shfl(my, min(sg + 24, cm), 32);
        float4 r0 = h4[(u0 & 0xFFFFu) * 4 + cq];
        float4 r1 = h4[(u1 & 0xFFFFu) * 4 + cq];
        float4 r2 = h4[(u2 & 0xFFFFu) * 4 + cq];
        float4 r3 = h4[(u3 & 0xFFFFu) * 4 + cq];
        float w0 = (sg      < c0) ? hdec(u0) : 0.0f;
        float w1 = (sg + 8  < c0) ? hdec(u1) : 0.0f;
        float w2 = (sg + 16 < c0) ? hdec(u2) : 0.0f;
        float w3 = (sg + 24 < c0) ? hdec(u3) : 0.0f;
        const __half2* p0 = reinterpret_cast<const __half2*>(&r0);
        const __half2* p1 = reinterpret_cast<const __half2*>(&r1);
        const __half2* p2 = reinterpret_cast<const __half2*>(&r2);
        const __half2* p3 = reinterpret_cast<const __half2*>(&r3);
#pragma unroll
        for (int i = 0; i < 4; ++i) {
            float2 f0 = __half22float2(p0[i]);
            float2 f1 = __half22float2(p1[i]);
            float2 f2 = __half22float2(p2[i]);
            float2 f3 = __half22float2(p3[i]);
            acc[2*i]   = fmaf(f0.x, w0, acc[2*i]);
            acc[2*i+1] = fmaf(f0.y, w0, acc[2*i+1]);
            acc[2*i]   = fmaf(f1.x, w1, acc[2*i]);
            acc[2*i+1] = fmaf(f1.y, w1, acc[2*i+1]);
            acc[2*i]   = fmaf(f2.x, w2, acc[2*i]);
            acc[2*i+1] = fmaf(f2.y, w2, acc[2*i+1]);
            acc[2*i]   = fmaf(f3.x, w3, acc[2*i]);
            acc[2*i+1] = fmaf(f3.y, w3, acc[2*i+1]);
        }
    }
#pragma unroll
    for (int off = 16; off >= 4; off >>= 1) {
#pragma unroll
        for (int i = 0; i < 8; ++i) acc[i] += __shfl_down(acc[i], off, 32);
    }
    if (ln < 4) {
        int col0 = half * 32 + cq * 8;
        float v[8];
#pragma unroll
        for (int i = 0; i < 8; ++i) v[i] = fmaf(acc[i], dd, bias[col0 + i]);
        float4* o = (float4*)out;
        o[node * 16 + half * 8 + cq * 2]     = make_float4(v[0], v[1], v[2], v[3]);
        o[node * 16 + half * 8 + cq * 2 + 1] = make_float4(v[4], v[5], v[6], v[7]);
        int lb = (t >> 5) * 32 + cq * 8;
#pragma unroll
        for (int i = 0; i < 8; ++i) { sm.s1[lb + i] = v[i]; sm.s2[lb + i] = v[i] * v[i]; }
    }
    __syncthreads();
#pragma unroll
    for (int off = 256; off >= 32; off >>= 1) {
        if (t < off) { sm.s1[t] += sm.s1[t + off]; sm.s2[t] += sm.s2[t + off]; }
        __syncthreads();
    }
    if (t < 32) {
        int cp = (vb >> 1) & (NCOPY - 1);
        int col = half * 32 + t;
        atomicAdd(&stat[cp * 128 + col],      sm.s1[t]);
        atomicAdd(&stat[cp * 128 + 64 + col], sm.s2[t]);
    }
    __syncthreads();   // s1/s2 reuse across persistent iterations
}

// ============ BN coefficient reduce (64 cols from NCOPY-spread stats) ======
__device__ __forceinline__ void bn_coef(int t, float* sc, float* sh,
        const float* stat, const float* gamma, const float* beta) {
    if (t < 64) {
        float s = 0.0f, q = 0.0f;
#pragma unroll 8
        for (int c = 0; c < NCOPY; ++c) {
            s += stat[c * 128 + t];
            q += stat[c * 128 + 64 + t];
        }
        const float invn = 1.0f / (float)N_NODES;
        float mean = s * invn;
        float var  = q * invn - mean * mean;   // biased, = jnp.var
        float g    = gamma[t] * rsqrtf(var + BN_EPS);
        sc[t] = g;
        sh[t] = beta[t] - mean * g;
    }
}

// ============ gemm2 tile (512 thr, 16 rows, 2 rows/thread) =================
// assumes g.sw / g.sc / g.sh already loaded + block synced.
__device__ __forceinline__ void gemm2_sub(int row0, int t, SmG2& g,
        const float* hin, const float* dinv, __half* ha, __half* hb) {
#pragma unroll
    for (int j = 0; j < 2; ++j) {
        int i = t + j * 512;
        int k = i & 63;
        g.sx[i] = fmaxf(0.0f, fmaf(hin[row0 * D_HID + i], g.sc[k], g.sh[k]));
    }
    __syncthreads();
    int c = t & 63, r2 = (t >> 6) * 2;
    float a0 = 0, a1 = 0;
#pragma unroll 4
    for (int k = 0; k < D_HID; ++k) {
        float w = g.sw[k * D_HID + c];
        a0 = fmaf(g.sx[(r2 + 0) * D_HID + k], w, a0);
        a1 = fmaf(g.sx[(r2 + 1) * D_HID + k], w, a1);
    }
    __half* tbl = (c < 32) ? ha : hb;
    int cc = c & 31;
    tbl[(row0 + r2 + 0) * 32 + cc] = __float2half_rn(a0 * dinv[row0 + r2 + 0]);
    tbl[(row0 + r2 + 1) * 32 + cc] = __float2half_rn(a1 * dinv[row0 + r2 + 1]);
    __syncthreads();   // sx reuse
}

// ============ MEGAKERNEL: binB -> gather1 -> gemm2 -> gather2 -> bnapply ===
// One cooperative launch replaces 5 dispatches (~10us boundary each, the
// largest budget item after k_pre per R0/R1/R3 cross-round arithmetic).
__global__ __launch_bounds__(512, 6) void k_mega(
        const int* bin_cur, const unsigned long long* binned,
        int2* row_se, float* dinv, __half* ha, __half* hb, unsigned int* csr,
        float* agg, float* stats, const float* b1,
        const float* g1, const float* be1, const float* W2,
        const float* b2, float* out, const float* g2, const float* be2) {
    __shared__ SmMega sm;
    int t = threadIdx.x;
    int nb = gridDim.x;
    cooperative_groups::grid_group gg = cooperative_groups::this_grid();

    // ---- phase A: zero spread stats + binB over 391 bins
    for (int i = blockIdx.x * 512 + t; i < 2 * NCOPY * 128; i += nb * 512)
        stats[i] = 0.0f;
    for (int bin = blockIdx.x; bin < NBINS; bin += nb)
        binB_body(bin, t, sm.b, bin_cur, binned, row_se, dinv, ha, hb, csr);
    gg.sync();

    // ---- phase B: gather layer 1 (BN1 stats into stats[0..])
    for (int vb = blockIdx.x; vb < NPAIR * 2; vb += nb)
        gather_body(vb, t, sm.s, ha, hb, csr, row_se, dinv, b1, agg, stats);
    gg.sync();

    // ---- phase C: gemm2 w/ BN1+ReLU fused input (coeffs + W loaded once)
    bn_coef(t, sm.g.sc, sm.g.sh, stats, g1, be1);
#pragma unroll
    for (int j = 0; j < 8; ++j) sm.g.sw[t + j * 512] = W2[t + j * 512];
    __syncthreads();
    for (int vb = blockIdx.x; vb < N_NODES / 16; vb += nb)
        gemm2_sub(vb * 16, t, sm.g, agg, dinv, ha, hb);
    gg.sync();

    // ---- phase D: gather layer 2 (BN2 stats into stats[NCOPY*128..])
    for (int vb = blockIdx.x; vb < NPAIR * 2; vb += nb)
        gather_body(vb, t, sm.s, ha, hb, csr, row_se, dinv, b2, out,
                    stats + NCOPY * 128);
    gg.sync();

    // ---- phase E: BN2 apply + ReLU in place on out
    bn_coef(t, sm.g.sc, sm.g.sh, stats + NCOPY * 128, g2, be2);
    __syncthreads();
    float4* o4 = (float4*)out;
    for (int i = blockIdx.x * 512 + t; i < N_NODES * 16; i += nb * 512) {
        int j = (i & 15) * 4;
        float4 v = o4[i];
        v.x = fmaxf(0.0f, fmaf(v.x, sm.g.sc[j],     sm.g.sh[j]));
        v.y = fmaxf(0.0f, fmaf(v.y, sm.g.sc[j + 1], sm.g.sh[j + 1]));
        v.z = fmaxf(0.0f, fmaf(v.z, sm.g.sc[j + 2], sm.g.sh[j + 2]));
        v.w = fmaxf(0.0f, fmaf(v.w, sm.g.sc[j + 3], sm.g.sh[j + 3]));
        o4[i] = v;
    }
}

// =============== fallback wrappers (plain launches, same bodies) ===========
__global__ __launch_bounds__(512) void k_binB_w(const int* bin_cur,
        const unsigned long long* binned, int2* row_se, float* dinv,
        __half* ha, __half* hb, unsigned int* csr) {
    __shared__ SmBinB s;
    binB_body(blockIdx.x, threadIdx.x, s, bin_cur, binned, row_se, dinv, ha, hb, csr);
}
__global__ __launch_bounds__(512) void k_gath_w(const __half* ha, const __half* hb,
        const unsigned int* csr, const int2* row_se, const float* dinv,
        const float* bias, float* out, float* stat) {
    __shared__ SmGath s;
    gather_body(blockIdx.x, threadIdx.x, s, ha, hb, csr, row_se, dinv, bias, out, stat);
}
__global__ __launch_bounds__(512) void k_g2_w(const float* hin, const float* stat,
        const float* gamma, const float* beta, const float* W,
        const float* dinv, __half* ha, __half* hb) {
    __shared__ SmG2 g;
    int t = threadIdx.x;
    bn_coef(t, g.sc, g.sh, stat, gamma, beta);
#pragma unroll
    for (int j = 0; j < 8; ++j) g.sw[t + j * 512] = W[t + j * 512];
    __syncthreads();
    gemm2_sub(blockIdx.x * 16, t, g, hin, dinv, ha, hb);
}
__global__ __launch_bounds__(512) void k_bnap_w(float4* h, const float* stat,
        const float* gamma, const float* beta) {
    __shared__ float sc[D_HID], sh[D_HID];
    int t = threadIdx.x;
    bn_coef(t, sc, sh, stat, gamma, beta);
    __syncthreads();
    for (int i = blockIdx.x * 512 + t; i < N_NODES * 16; i += gridDim.x * 512) {
        int j = (i & 15) * 4;
        float4 v = h[i];
        v.x = fmaxf(0.0f, fmaf(v.x, sc[j],     sh[j]));
        v.y = fmaxf(0.0f, fmaf(v.y, sc[j + 1], sh[j + 1]));
        v.z = fmaxf(0.0f, fmaf(v.z, sc[j + 2], sh[j + 2]));
        v.w = fmaxf(0.0f, fmaf(v.w, sc[j + 3], sh[j + 3]));
        h[i] = v;
    }
}

extern "C" void kernel_launch(void* const* d_in, const int* in_sizes, int n_in,
                              void* d_out, int out_size, void* d_ws, size_t ws_size,
                              hipStream_t stream) {
    const float* x     = (const float*)d_in[0];
    const int*   ei_sc = (const int*)  d_in[1];   // [2*E] src then dst
    const float* w_sc  = (const float*)d_in[2];
    const float* w_fc  = (const float*)d_in[4];
    const float* alpha = (const float*)d_in[5];
    const float* W1    = (const float*)d_in[6];
    const float* b1    = (const float*)d_in[7];
    const float* W2    = (const float*)d_in[8];
    const float* b2    = (const float*)d_in[9];
    const float* g1    = (const float*)d_in[10];
    const float* be1   = (const float*)d_in[11];
    const float* g2    = (const float*)d_in[12];
    const float* be2   = (const float*)d_in[13];
    float* out = (float*)d_out;

    // ---- workspace layout (R3-verbatim, all segments 16B-aligned): ~41.5 MB
    unsigned long long* binned = (unsigned long long*)d_ws;        // NBINS*BINCAP u64
    int2*  row_se  = (int2*)(binned + (size_t)NBINS * BINCAP);     // N int2
    int*   bin_cur = (int*)(row_se + N_NODES);                     // 400 (391 used)
    float* stats   = (float*)(bin_cur + 400);                      // 2*NCOPY*128
    float* dinv    = stats + 2 * NCOPY * 128;                      // N
    unsigned int* csr = (unsigned int*)(dinv + N_NODES);           // NBINS*BINCAP
    __half* ha     = (__half*)(csr + (size_t)NBINS * BINCAP);      // N*32 halves
    __half* hb     = ha + (size_t)N_NODES * 32;                    // N*32 halves
    float* agg     = (float*)(hb + (size_t)N_NODES * 32);          // N*64

    // ---- memset covers bin_cur + both stat layers (mega re-zeroes stats
    // in phase A too, so the fallback path is also correct).
    hipMemsetAsync(bin_cur, 0, (400 + 2 * NCOPY * 128) * sizeof(int), stream);
    k_pre<<<256 + GEMM1B, 256, 0, stream>>>(w_sc, w_fc, ei_sc, alpha,
                                            bin_cur, binned, x, W1, ha, hb);

    // ---- cooperative megakernel: grid sized for guaranteed co-residency
    static int bpc = 0;
    if (bpc == 0) {
        int v = 0;
        if (hipOccupancyMaxActiveBlocksPerMultiprocessor(&v, k_mega, 512, 0)
                == hipSuccess && v > 0) bpc = v;
        else bpc = 2;                 // 2 blocks/CU always fits (79KB LDS, <=85 VGPR)
        if (bpc > 4) bpc = 4;         // LDS cap: 4 x 39.4KB = 158KB
    }
    int nb = bpc * 256;               // MI355X: 256 CUs

    const int*   a_bc = bin_cur;  const unsigned long long* a_bn = binned;
    int2*  a_rs = row_se;  float* a_dv = dinv;
    __half* a_ha = ha;     __half* a_hb = hb;   unsigned int* a_cs = csr;
    float* a_ag = agg;     float* a_st = stats;
    const float* a_b1 = b1, *a_g1 = g1, *a_e1 = be1, *a_w2 = W2;
    const float* a_b2 = b2, *a_g2 = g2, *a_e2 = be2;
    float* a_ou = out;
    void* margs[] = { (void*)&a_bc, (void*)&a_bn, (void*)&a_rs, (void*)&a_dv,
                      (void*)&a_ha, (void*)&a_hb, (void*)&a_cs, (void*)&a_ag,
                      (void*)&a_st, (void*)&a_b1, (void*)&a_g1, (void*)&a_e1,
                      (void*)&a_w2, (void*)&a_b2, (void*)&a_ou, (void*)&a_g2,
                      (void*)&a_e2 };
    hipError_t ce = hipLaunchCooperativeKernel((const void*)k_mega, dim3(nb),
                                               dim3(512), margs, 0, stream);
    if (ce != hipSuccess) {
        // -------- fallback: plain sequential launches of the same bodies
        k_binB_w<<<NBINS, 512, 0, stream>>>(bin_cur, binned, row_se, dinv,
                                            ha, hb, csr);
        k_gath_w<<<NPAIR * 2, 512, 0, stream>>>(ha, hb, csr, row_se, dinv,
                                                b1, agg, stats);
        k_g2_w  <<<N_NODES / 16, 512, 0, stream>>>(agg, stats, g1, be1, W2,
                                                   dinv, ha, hb);
        k_gath_w<<<NPAIR * 2, 512, 0, stream>>>(ha, hb, csr, row_se, dinv,
                                                b2, out, stats + NCOPY * 128);
        k_bnap_w<<<1563, 512, 0, stream>>>((float4*)out, stats + NCOPY * 128,
                                           g2, be2);
    }
}

// Round 6
// 290.183 us; speedup vs baseline: 1.8525x; 1.8525x over previous
//
#include <hip/hip_runtime.h>
#include <hip/hip_fp16.h>
#include <math.h>

#define N_NODES 50000
#define N_EDGES 1600000
#define D_INF   128
#define D_HID   64
#define BN_EPS  1e-5f
#define NBINS   782      // fine bins, 64 nodes each (bin = dst >> 6)
#define BINCAP  2432     // per-bin cap (mean 2046, +8.5 sigma)
#define EPB     6250     // edges per binA block (256 blocks x 6250 = E)
#define GEMM1B  3125     // gemm1 blocks inside k_pre
#define NPAIR   3125     // gather block-pairs (16 nodes each)
#define NCOPY   64       // BN stat accumulator copies (atomic spread)

// ============ fused k_pre: blocks 0..255 binA | 256..3380 gemm1 ============
// binA: R9's 2-pass shared-hist form (floor ~50us). R6: 64-node bins
// (binB occupancy fix); entry node-local index is now (d & 63).
// R4 lesson kept: binned writes stay XCD-line-dense (direct scatter = 8x
// write amplification). R5 lesson: no multi-phase persistent kernels
// (shared regalloc kills gather MLP).
// gemm1 writes SPLIT half-tables ha (cols 0-31) / hb (cols 32-63).
struct SmGemm { float sw[D_INF * D_HID]; float sx[16 * D_INF]; };  // 40 KB
struct SmBin  { int hcnt[NBINS]; int hbase[NBINS]; };              // 6.3 KB
union SmPre { SmGemm g; SmBin a; };

__global__ __launch_bounds__(256) void k_pre(const float* __restrict__ wsc,
                                             const float* __restrict__ wfc,
                                             const int*   __restrict__ ei,
                                             const float* __restrict__ alpha,
                                             int* __restrict__ bin_cur,
                                             unsigned long long* __restrict__ binned,
                                             const float* __restrict__ x,
                                             const float* __restrict__ W,
                                             __half* __restrict__ ha,
                                             __half* __restrict__ hb) {
    __shared__ SmPre sm;
    int t = threadIdx.x;
    if (blockIdx.x < 256) {
        // ---------------- binA: bin edges by dst>>6, staged coalesced ------
        int e0 = blockIdx.x * EPB;
        for (int b = t; b < NBINS; b += 256) sm.a.hcnt[b] = 0;
        __syncthreads();
        for (int i = t; i < EPB; i += 256)
            atomicAdd(&sm.a.hcnt[ei[N_EDGES + e0 + i] >> 6], 1);
        __syncthreads();
        for (int b = t; b < NBINS; b += 256) {
            int c = sm.a.hcnt[b];
            sm.a.hbase[b] = c ? atomicAdd(&bin_cur[b], c) : 0;
            sm.a.hcnt[b] = 0;
        }
        __syncthreads();
        float a = 1.0f / (1.0f + expf(-alpha[0]));
        for (int i = t; i < EPB; i += 256) {
            int e = e0 + i;
            int s = ei[e], d = ei[N_EDGES + e];
            float wm = fmaf(a, wsc[e] - wfc[e], wfc[e]);   // a*wsc+(1-a)*wfc
            int bin = d >> 6;
            int slot = atomicAdd(&sm.a.hcnt[bin], 1);
            int gpos = sm.a.hbase[bin] + slot;
            if (gpos < BINCAP) {
                unsigned long long ent =
                    ((unsigned long long)__float_as_uint(wm) << 32)
                    | (unsigned int)(s | ((d & 63) << 16));
                binned[(size_t)bin * BINCAP + gpos] = ent;
            }
        }
    } else {
        // ---------------- gemm1: [N,128]x[128,64] -> fp16 halves -----------
        int row0 = (blockIdx.x - 256) * 16;
#pragma unroll
        for (int j = 0; j < 32; ++j) sm.g.sw[t + j * 256] = W[t + j * 256];
#pragma unroll
        for (int j = 0; j < 8; ++j) {
            int i = t + j * 256;
            int r = i >> 7, k = i & 127;
            sm.g.sx[i] = x[(row0 + r) * D_INF + k];
        }
        __syncthreads();
        int c = t & 63, rg = (t >> 6) * 4;
        float a0 = 0, a1 = 0, a2 = 0, a3 = 0;
#pragma unroll 4
        for (int k = 0; k < D_INF; ++k) {
            float w = sm.g.sw[k * D_HID + c];
            a0 = fmaf(sm.g.sx[(rg + 0) * D_INF + k], w, a0);
            a1 = fmaf(sm.g.sx[(rg + 1) * D_INF + k], w, a1);
            a2 = fmaf(sm.g.sx[(rg + 2) * D_INF + k], w, a2);
            a3 = fmaf(sm.g.sx[(rg + 3) * D_INF + k], w, a3);
        }
        __half* tbl = (c < 32) ? ha : hb;
        int cc = c & 31;
        tbl[(row0 + rg + 0) * 32 + cc] = __float2half_rn(a0);
        tbl[(row0 + rg + 1) * 32 + cc] = __float2half_rn(a1);
        tbl[(row0 + rg + 2) * 32 + cc] = __float2half_rn(a2);
        tbl[(row0 + rg + 3) * 32 + cc] = __float2half_rn(a3);
    }
}

// ====== merged phase B (512 thr): LDS-stage entries once; hist -> dinv,
// row_se; scale h by dinv; fill csr. h' = dinv*h fold, csr stores wm only.
// R6: 64-node bins -> stage 19.5KB (was 36.9), ~3 blocks/CU resident
// (was ~1.5) so the 14.4MB HBM staging read is latency-hidden.
__global__ __launch_bounds__(512) void k_binB(const int* __restrict__ bin_cur,
                                              const unsigned long long* __restrict__ binned,
                                              int2*  __restrict__ row_se,
                                              float* __restrict__ dinv,
                                              __half* __restrict__ ha,
                                              __half* __restrict__ hb,
                                              unsigned int* __restrict__ csr) {
    __shared__ unsigned long long stage[BINCAP];   // 19.5 KB
    __shared__ int   ncnt[64];
    __shared__ float ndeg[64];
    __shared__ int   sscan[64];
    __shared__ float sdinv[64];
    __shared__ int   lb[64];
    int t = threadIdx.x;
    int bin = blockIdx.x;
    if (t < 64) { ncnt[t] = 0; ndeg[t] = 0.0f; }
    int cnt = min(bin_cur[bin], BINCAP);
    const unsigned long long* mybin = binned + (size_t)bin * BINCAP;
    for (int i = t; i < cnt; i += 512) stage[i] = mybin[i];
    __syncthreads();
    for (int i = t; i < cnt; i += 512) {
        unsigned long long ent = stage[i];
        unsigned int lo = (unsigned int)ent;
        int nl = (lo >> 16) & 63;
        float wm = __uint_as_float((unsigned int)(ent >> 32));
        atomicAdd(&ncnt[nl], 1);
        atomicAdd(&ndeg[nl], wm);
    }
    __syncthreads();
    int node0 = bin << 6;
    int nnodes = min(64, N_NODES - node0);
    if (t < 64) {
        float dv = rsqrtf(1.0f + ndeg[t]);   // +1 self loop
        sdinv[t] = dv;
        if (t < nnodes) dinv[node0 + t] = dv;
        sscan[t] = ncnt[t];
    }
    __syncthreads();
    for (int off = 1; off < 64; off <<= 1) {
        int u = (t >= off && t < 64) ? sscan[t - off] : 0;
        __syncthreads();
        if (t < 64) sscan[t] += u;
        __syncthreads();
    }
    if (t < nnodes) {
        int s = bin * BINCAP + sscan[t] - ncnt[t];
        row_se[node0 + t] = make_int2(s, s + ncnt[t]);
        lb[t] = s;
    }
    __syncthreads();
    // scale this bin's h rows by dinv (coalesced, 8 KB)
    int nh = nnodes * 32;
    for (int i = t; i < nh; i += 512) {
        int n = i >> 5, c = i & 31;
        float dv = sdinv[n];
        int idx = (node0 + n) * 32 + c;
        ha[idx] = __float2half_rn(__half2float(ha[idx]) * dv);
        hb[idx] = __float2half_rn(__half2float(hb[idx]) * dv);
    }
    if (t < 64) ncnt[t] = 0;   // reuse as fill cursor
    __syncthreads();
    for (int i = t; i < cnt; i += 512) {
        unsigned long long ent = stage[i];
        unsigned int lo = (unsigned int)ent;
        int nl  = (lo >> 16) & 63;
        int src = lo & 0xFFFFu;
        float wm = __uint_as_float((unsigned int)(ent >> 32));
        int slot = atomicAdd(&ncnt[nl], 1);
        unsigned short wh = __half_as_ushort(__float2half_rn(wm));
        csr[lb[nl] + slot] = (unsigned int)src | ((unsigned int)wh << 16);
    }
}

__device__ inline float hdec(unsigned int u) {
    return __half2float(__ushort_as_half((unsigned short)(u >> 16)));
}

// == gather (512 thr, R3-verbatim): WIDE 16B/lane table reads (123->38us
// measured). cq=ln&3 picks a float4 (8 halves) of the 64B row; sg=ln>>2
// picks the edge -> 8 edges per load step, 4 lane-addresses/edge.
// BN stats: block LDS reduce -> atomics spread over NCOPY copies
// (R1 lesson: 128 addresses x 3125 serialized adds = +70us/launch).
// out[d] = dd * ( sum_e wm_e * h'[s_e] + h'[d] ) + bias   (h' = dinv*h)
__global__ __launch_bounds__(512) void k_gather(const __half* __restrict__ ha,
                                                const __half* __restrict__ hb,
                                                const unsigned int* __restrict__ csr,
                                                const int2*  __restrict__ row_se,
                                                const float* __restrict__ dinv,
                                                const float* __restrict__ bias,
                                                float* __restrict__ out,
                                                float* __restrict__ stat) {
    __shared__ float s1[512], s2[512];
    int t = threadIdx.x;
    int half = blockIdx.x & 1;
    const float4* __restrict__ h4 = (const float4*)(half ? hb : ha);
    int node = (blockIdx.x >> 1) * 16 + (t >> 5);
    int ln = t & 31;
    int sg = ln >> 2;     // 0..7: edge subgroup
    int cq = ln & 3;      // 0..3: column quad (8 cols = 16B)
    int2 se = row_se[node];
    float dd = dinv[node];
    float acc[8];
    if (sg == 0) {        // self term (pre-scaled by dinv), added once
        float4 sv = h4[node * 4 + cq];
        const __half2* p = reinterpret_cast<const __half2*>(&sv);
#pragma unroll
        for (int i = 0; i < 4; ++i) {
            float2 f = __half22float2(p[i]);
            acc[2 * i] = f.x; acc[2 * i + 1] = f.y;
        }
    } else {
#pragma unroll
        for (int i = 0; i < 8; ++i) acc[i] = 0.0f;
    }
    for (int b = se.x; b < se.y; b += 32) {
        int c0 = min(32, se.y - b);
        int cm = c0 - 1;
        unsigned int my = (ln < c0) ? csr[b + ln] : 0u;
        // 4 masked steps x 8 edges; clamp keeps addresses valid, w=0 kills
        // the contribution. Poisson(32) degrees => <15% wasted slots.
        unsigned int u0 = __shfl(my, min(sg,      cm), 32);
        unsigned int u1 = __shfl(my, min(sg + 8,  cm), 32);
        unsigned int u2 = __shfl(my, min(sg + 16, cm), 32);
        unsigned int u3 = __shfl(my, min(sg + 24, cm), 32);
        float4 r0 = h4[(u0 & 0xFFFFu) * 4 + cq];
        float4 r1 = h4[(u1 & 0xFFFFu) * 4 + cq];
        float4 r2 = h4[(u2 & 0xFFFFu) * 4 + cq];
        float4 r3 = h4[(u3 & 0xFFFFu) * 4 + cq];
        float w0 = (sg      < c0) ? hdec(u0) : 0.0f;
        float w1 = (sg + 8  < c0) ? hdec(u1) : 0.0f;
        float w2 = (sg + 16 < c0) ? hdec(u2) : 0.0f;
        float w3 = (sg + 24 < c0) ? hdec(u3) : 0.0f;
        const __half2* p0 = reinterpret_cast<const __half2*>(&r0);
        const __half2* p1 = reinterpret_cast<const __half2*>(&r1);
        const __half2* p2 = reinterpret_cast<const __half2*>(&r2);
        const __half2* p3 = reinterpret_cast<const __half2*>(&r3);
#pragma unroll
        for (int i = 0; i < 4; ++i) {
            float2 f0 = __half22float2(p0[i]);
            float2 f1 = __half22float2(p1[i]);
            float2 f2 = __half22float2(p2[i]);
            float2 f3 = __half22float2(p3[i]);
            acc[2*i]   = fmaf(f0.x, w0, acc[2*i]);
            acc[2*i+1] = fmaf(f0.y, w0, acc[2*i+1]);
            acc[2*i]   = fmaf(f1.x, w1, acc[2*i]);
            acc[2*i+1] = fmaf(f1.y, w1, acc[2*i+1]);
            acc[2*i]   = fmaf(f2.x, w2, acc[2*i]);
            acc[2*i+1] = fmaf(f2.y, w2, acc[2*i+1]);
            acc[2*i]   = fmaf(f3.x, w3, acc[2*i]);
            acc[2*i+1] = fmaf(f3.y, w3, acc[2*i+1]);
        }
    }
    // fold 8 edge-subgroups (stride-4 lanes) -> lanes 0..3 hold 32 cols
#pragma unroll
    for (int off = 16; off >= 4; off >>= 1) {
#pragma unroll
        for (int i = 0; i < 8; ++i) acc[i] += __shfl_down(acc[i], off, 32);
    }
    if (ln < 4) {
        int col0 = half * 32 + cq * 8;
        float v[8];
#pragma unroll
        for (int i = 0; i < 8; ++i) v[i] = fmaf(acc[i], dd, bias[col0 + i]);
        float4* o = (float4*)out;
        o[node * 16 + half * 8 + cq * 2]     = make_float4(v[0], v[1], v[2], v[3]);
        o[node * 16 + half * 8 + cq * 2 + 1] = make_float4(v[4], v[5], v[6], v[7]);
        int lb = (t >> 5) * 32 + cq * 8;
#pragma unroll
        for (int i = 0; i < 8; ++i) { s1[lb + i] = v[i]; s2[lb + i] = v[i] * v[i]; }
    }
    __syncthreads();
#pragma unroll
    for (int off = 256; off >= 32; off >>= 1) {
        if (t < off) { s1[t] += s1[t + off]; s2[t] += s2[t + off]; }
        __syncthreads();
    }
    if (t < 32) {
        int cp = (blockIdx.x >> 1) & (NCOPY - 1);
        int col = half * 32 + t;
        atomicAdd(&stat[cp * 128 + col],      s1[t]);
        atomicAdd(&stat[cp * 128 + 64 + col], s2[t]);
    }
}

// == GEMM2 fused BN1+ReLU in, dinv-scaled split fp16 out: [N,64]x[64,64] ====
// BN scale/shift computed inline from NCOPY-spread stat accumulators.
__global__ __launch_bounds__(256) void k_gemm2_bn(const float* __restrict__ hin,
                                                  const float* __restrict__ stat,
                                                  const float* __restrict__ gamma,
                                                  const float* __restrict__ beta,
                                                  const float* __restrict__ W,
                                                  const float* __restrict__ dinv,
                                                  __half* __restrict__ ha,
                                                  __half* __restrict__ hb) {
    __shared__ float sw[D_HID * D_HID];   // 16 KB
    __shared__ float sx[16 * D_HID];      // 4 KB
    __shared__ float sc[D_HID], sh[D_HID];
    int t = threadIdx.x;
    int row0 = blockIdx.x * 16;
#pragma unroll
    for (int j = 0; j < 16; ++j) sw[t + j * 256] = W[t + j * 256];
    if (t < 64) {
        float s = 0.0f, q = 0.0f;
#pragma unroll 8
        for (int c = 0; c < NCOPY; ++c) {
            s += stat[c * 128 + t];
            q += stat[c * 128 + 64 + t];
        }
        const float invn = 1.0f / (float)N_NODES;
        float mean = s * invn;
        float var  = q * invn - mean * mean;   // biased, = jnp.var
        float g    = gamma[t] * rsqrtf(var + BN_EPS);
        sc[t] = g;
        sh[t] = beta[t] - mean * g;
    }
    __syncthreads();
#pragma unroll
    for (int j = 0; j < 4; ++j) {
        int i = t + j * 256;
        int k = i & 63;
        sx[i] = fmaxf(0.0f, fmaf(hin[row0 * D_HID + i], sc[k], sh[k]));
    }
    __syncthreads();
    int c = t & 63, rg = (t >> 6) * 4;
    float a0 = 0, a1 = 0, a2 = 0, a3 = 0;
#pragma unroll 4
    for (int k = 0; k < D_HID; ++k) {
        float w = sw[k * D_HID + c];
        a0 = fmaf(sx[(rg + 0) * D_HID + k], w, a0);
        a1 = fmaf(sx[(rg + 1) * D_HID + k], w, a1);
        a2 = fmaf(sx[(rg + 2) * D_HID + k], w, a2);
        a3 = fmaf(sx[(rg + 3) * D_HID + k], w, a3);
    }
    __half* tbl = (c < 32) ? ha : hb;
    int cc = c & 31;
    tbl[(row0 + rg + 0) * 32 + cc] = __float2half_rn(a0 * dinv[row0 + rg + 0]);
    tbl[(row0 + rg + 1) * 32 + cc] = __float2half_rn(a1 * dinv[row0 + rg + 1]);
    tbl[(row0 + rg + 2) * 32 + cc] = __float2half_rn(a2 * dinv[row0 + rg + 2]);
    tbl[(row0 + rg + 3) * 32 + cc] = __float2half_rn(a3 * dinv[row0 + rg + 3]);
}

// ====== BN apply + ReLU (in place, float4); coeffs from spread stats =======
__global__ __launch_bounds__(256) void k_bn_apply_relu(float4* __restrict__ h,
                                                       const float* __restrict__ stat,
                                                       const float* __restrict__ gamma,
                                                       const float* __restrict__ beta) {
    __shared__ float sc[D_HID], sh[D_HID];
    int t = threadIdx.x;
    if (t < 64) {
        float s = 0.0f, q = 0.0f;
#pragma unroll 8
        for (int c = 0; c < NCOPY; ++c) {
            s += stat[c * 128 + t];
            q += stat[c * 128 + 64 + t];
        }
        const float invn = 1.0f / (float)N_NODES;
        float mean = s * invn;
        float var  = q * invn - mean * mean;
        float g    = gamma[t] * rsqrtf(var + BN_EPS);
        sc[t] = g;
        sh[t] = beta[t] - mean * g;
    }
    __syncthreads();
    int idx = blockIdx.x * 256 + t;
    if (idx >= N_NODES * D_HID / 4) return;
    int j = (idx & 15) * 4;
    float4 v = h[idx];
    v.x = fmaxf(0.0f, fmaf(v.x, sc[j],     sh[j]));
    v.y = fmaxf(0.0f, fmaf(v.y, sc[j + 1], sh[j + 1]));
    v.z = fmaxf(0.0f, fmaf(v.z, sc[j + 2], sh[j + 2]));
    v.w = fmaxf(0.0f, fmaf(v.w, sc[j + 3], sh[j + 3]));
    h[idx] = v;
}

extern "C" void kernel_launch(void* const* d_in, const int* in_sizes, int n_in,
                              void* d_out, int out_size, void* d_ws, size_t ws_size,
                              hipStream_t stream) {
    const float* x     = (const float*)d_in[0];
    const int*   ei_sc = (const int*)  d_in[1];   // [2*E] src then dst
    const float* w_sc  = (const float*)d_in[2];
    const float* w_fc  = (const float*)d_in[4];
    const float* alpha = (const float*)d_in[5];
    const float* W1    = (const float*)d_in[6];
    const float* b1    = (const float*)d_in[7];
    const float* W2    = (const float*)d_in[8];
    const float* b2    = (const float*)d_in[9];
    const float* g1    = (const float*)d_in[10];
    const float* be1   = (const float*)d_in[11];
    const float* g2    = (const float*)d_in[12];
    const float* be2   = (const float*)d_in[13];
    float* out = (float*)d_out;

    // ---- workspace layout, all segments 16B-aligned: ~42.7 MB
    // binned | row_se | bin_cur(800 pad) | stats | dinv | csr | ha | hb | agg
    unsigned long long* binned = (unsigned long long*)d_ws;        // NBINS*BINCAP u64
    int2*  row_se  = (int2*)(binned + (size_t)NBINS * BINCAP);     // N int2
    int*   bin_cur = (int*)(row_se + N_NODES);                     // 800 (782 used)
    float* stats   = (float*)(bin_cur + 800);                      // 2*NCOPY*128
    float* dinv    = stats + 2 * NCOPY * 128;                      // N
    unsigned int* csr = (unsigned int*)(dinv + N_NODES);           // NBINS*BINCAP
    __half* ha     = (__half*)(csr + (size_t)NBINS * BINCAP);      // N*32 halves
    __half* hb     = ha + (size_t)N_NODES * 32;                    // N*32 halves
    float* agg     = (float*)(hb + (size_t)N_NODES * 32);          // N*64

    const int gV4 = (N_NODES * D_HID / 4 + 255) / 256;             // 3125
    const int gGA = NPAIR * 2;                                     // 6250
    const int gGM = N_NODES / 16;                                  // 3125

    // ---- fused binA+gemm1, then merged CSR build (+dinv fold into h).
    // one memset covers bin_cur AND both layers' spread stat accumulators.
    hipMemsetAsync(bin_cur, 0, (800 + 2 * NCOPY * 128) * sizeof(int), stream);
    k_pre <<<256 + GEMM1B, 256, 0, stream>>>(w_sc, w_fc, ei_sc, alpha,
                                             bin_cur, binned, x, W1, ha, hb);
    k_binB<<<NBINS, 512, 0, stream>>>(bin_cur, binned, row_se, dinv, ha, hb, csr);

    // ---- layer 1 (BN stats spread-atomic accumulated in gather epilogue)
    k_gather  <<<gGA, 512, 0, stream>>>(ha, hb, csr, row_se, dinv, b1, agg, stats);

    // ---- layer 2 (BN1+ReLU coeffs computed inline; dinv folded into output)
    k_gemm2_bn<<<gGM, 256, 0, stream>>>(agg, stats, g1, be1, W2, dinv, ha, hb);
    k_gather  <<<gGA, 512, 0, stream>>>(ha, hb, csr, row_se, dinv, b2, out,
                                        stats + NCOPY * 128);
    k_bn_apply_relu<<<gV4, 256, 0, stream>>>((float4*)out, stats + NCOPY * 128,
                                             g2, be2);
}

// Round 7
// 276.638 us; speedup vs baseline: 1.9432x; 1.0490x over previous
//
#include <hip/hip_runtime.h>
#include <hip/hip_fp16.h>
#include <math.h>

#define N_NODES 50000
#define N_EDGES 1600000
#define D_INF   128
#define D_HID   64
#define BN_EPS  1e-5f
#define NBINS   391      // fine bins, 128 nodes each (bin = dst >> 7)  [R3 best]
#define BINCAP  4608     // per-bin cap (mean 4092, +8 sigma)
#define EPB     6250     // edges per binA block (256 blocks x 6250 = E)
#define GEMM1B  3125     // gemm1 blocks inside k_pre
#define NPAIR   3125     // gather block-pairs (16 nodes each)
#define NCOPY   64       // BN stat accumulator copies (atomic spread)

// ============ fused k_pre: blocks 0..255 binA | 256..3380 gemm1 ============
// R3-verbatim. Ledger: 391 bins beats 782 (R6: halving bin size made each
// binA per-bin write run ~1 line -> WRITE_SIZE 36->46MB, k_pre +7us).
// R4: direct per-node CSR scatter = 8x XCD write amplification. R5: no
// multi-phase persistent kernels (shared regalloc kills gather MLP).
struct SmGemm { float sw[D_INF * D_HID]; float sx[16 * D_INF]; };  // 40 KB
struct SmBin  { int hcnt[NBINS]; int hbase[NBINS]; };              // 3.1 KB
union SmPre { SmGemm g; SmBin a; };

__global__ __launch_bounds__(256) void k_pre(const float* __restrict__ wsc,
                                             const float* __restrict__ wfc,
                                             const int*   __restrict__ ei,
                                             const float* __restrict__ alpha,
                                             int* __restrict__ bin_cur,
                                             unsigned long long* __restrict__ binned,
                                             const float* __restrict__ x,
                                             const float* __restrict__ W,
                                             __half* __restrict__ ha,
                                             __half* __restrict__ hb) {
    __shared__ SmPre sm;
    int t = threadIdx.x;
    if (blockIdx.x < 256) {
        // ---------------- binA: bin edges by dst>>7, staged coalesced ------
        int e0 = blockIdx.x * EPB;
        for (int b = t; b < NBINS; b += 256) sm.a.hcnt[b] = 0;
        __syncthreads();
        for (int i = t; i < EPB; i += 256)
            atomicAdd(&sm.a.hcnt[ei[N_EDGES + e0 + i] >> 7], 1);
        __syncthreads();
        for (int b = t; b < NBINS; b += 256) {
            int c = sm.a.hcnt[b];
            sm.a.hbase[b] = c ? atomicAdd(&bin_cur[b], c) : 0;
            sm.a.hcnt[b] = 0;
        }
        __syncthreads();
        float a = 1.0f / (1.0f + expf(-alpha[0]));
        for (int i = t; i < EPB; i += 256) {
            int e = e0 + i;
            int s = ei[e], d = ei[N_EDGES + e];
            float wm = fmaf(a, wsc[e] - wfc[e], wfc[e]);   // a*wsc+(1-a)*wfc
            int bin = d >> 7;
            int slot = atomicAdd(&sm.a.hcnt[bin], 1);
            int gpos = sm.a.hbase[bin] + slot;
            if (gpos < BINCAP) {
                unsigned long long ent =
                    ((unsigned long long)__float_as_uint(wm) << 32)
                    | (unsigned int)(s | ((d & 127) << 16));
                binned[(size_t)bin * BINCAP + gpos] = ent;
            }
        }
    } else {
        // ---------------- gemm1: [N,128]x[128,64] -> fp16 halves -----------
        int row0 = (blockIdx.x - 256) * 16;
#pragma unroll
        for (int j = 0; j < 32; ++j) sm.g.sw[t + j * 256] = W[t + j * 256];
#pragma unroll
        for (int j = 0; j < 8; ++j) {
            int i = t + j * 256;
            int r = i >> 7, k = i & 127;
            sm.g.sx[i] = x[(row0 + r) * D_INF + k];
        }
        __syncthreads();
        int c = t & 63, rg = (t >> 6) * 4;
        float a0 = 0, a1 = 0, a2 = 0, a3 = 0;
#pragma unroll 4
        for (int k = 0; k < D_INF; ++k) {
            float w = sm.g.sw[k * D_HID + c];
            a0 = fmaf(sm.g.sx[(rg + 0) * D_INF + k], w, a0);
            a1 = fmaf(sm.g.sx[(rg + 1) * D_INF + k], w, a1);
            a2 = fmaf(sm.g.sx[(rg + 2) * D_INF + k], w, a2);
            a3 = fmaf(sm.g.sx[(rg + 3) * D_INF + k], w, a3);
        }
        __half* tbl = (c < 32) ? ha : hb;
        int cc = c & 31;
        tbl[(row0 + rg + 0) * 32 + cc] = __float2half_rn(a0);
        tbl[(row0 + rg + 1) * 32 + cc] = __float2half_rn(a1);
        tbl[(row0 + rg + 2) * 32 + cc] = __float2half_rn(a2);
        tbl[(row0 + rg + 3) * 32 + cc] = __float2half_rn(a3);
    }
}

// ====== merged phase B (512 thr): LDS-stage entries once; hist -> dinv,
// row_se; scale h by dinv; fill csr. h' = dinv*h fold, csr stores wm only.
// R7: pass-1 count+ndeg merged into ONE u64 LDS atomic (count<<48 |
// wm in 2^-32 fixed point; max 4608*2^32 = 2^44 < 2^48, no overflow;
// quantization ~1e-8 on deg, invisible under fp16-table absmax). h-scale
// vectorized __half2. (R6 refuted occupancy as binB's binder -- atomic
// work content is the remaining lever.)
__global__ __launch_bounds__(512) void k_binB(const int* __restrict__ bin_cur,
                                              const unsigned long long* __restrict__ binned,
                                              int2*  __restrict__ row_se,
                                              float* __restrict__ dinv,
                                              __half* __restrict__ ha,
                                              __half* __restrict__ hb,
                                              unsigned int* __restrict__ csr) {
    __shared__ unsigned long long stage[BINCAP];   // 36.9 KB
    __shared__ unsigned long long nacc[128];       // count<<48 | fixed ndeg
    __shared__ int   ncnt[128];
    __shared__ int   sscan[128];
    __shared__ float sdinv[128];
    __shared__ int   lb[128];
    int t = threadIdx.x;
    int bin = blockIdx.x;
    if (t < 128) nacc[t] = 0ULL;
    int cnt = min(bin_cur[bin], BINCAP);
    const unsigned long long* mybin = binned + (size_t)bin * BINCAP;
    for (int i = t; i < cnt; i += 512) stage[i] = mybin[i];
    __syncthreads();
    for (int i = t; i < cnt; i += 512) {
        unsigned long long ent = stage[i];
        unsigned int lo = (unsigned int)ent;
        int nl = (lo >> 16) & 127;
        float wm = __uint_as_float((unsigned int)(ent >> 32));
        unsigned long long pk = (1ULL << 48)
            | (unsigned long long)(wm * 4294967296.0f);
        atomicAdd(&nacc[nl], pk);
    }
    __syncthreads();
    int node0 = bin << 7;
    int nnodes = min(128, N_NODES - node0);
    if (t < 128) {
        unsigned long long v = nacc[t];
        int c = (int)(v >> 48);
        float nd = (float)(v & 0xFFFFFFFFFFFFULL) * 2.3283064365386963e-10f;
        float dv = rsqrtf(1.0f + nd);   // +1 self loop
        sdinv[t] = dv;
        if (t < nnodes) dinv[node0 + t] = dv;
        ncnt[t] = c;
        sscan[t] = c;
    }
    __syncthreads();
    for (int off = 1; off < 128; off <<= 1) {
        int u = (t >= off && t < 128) ? sscan[t - off] : 0;
        __syncthreads();
        if (t < 128) sscan[t] += u;
        __syncthreads();
    }
    if (t < nnodes) {
        int s = bin * BINCAP + sscan[t] - ncnt[t];
        row_se[node0 + t] = make_int2(s, s + ncnt[t]);
        lb[t] = s;
    }
    __syncthreads();
    // scale this bin's h rows by dinv (vectorized __half2, 4 B/lane)
    int nh = nnodes * 16;   // __half2 per table (32 cols = 16 half2)
    __half2* pa = (__half2*)ha;
    __half2* pb = (__half2*)hb;
    for (int i = t; i < nh; i += 512) {
        int n = i >> 4;
        float dv = sdinv[n];
        int idx = node0 * 16 + i;
        float2 fa = __half22float2(pa[idx]);
        float2 fb = __half22float2(pb[idx]);
        pa[idx] = __floats2half2_rn(fa.x * dv, fa.y * dv);
        pb[idx] = __floats2half2_rn(fb.x * dv, fb.y * dv);
    }
    if (t < 128) ncnt[t] = 0;   // reuse as fill cursor
    __syncthreads();
    for (int i = t; i < cnt; i += 512) {
        unsigned long long ent = stage[i];
        unsigned int lo = (unsigned int)ent;
        int nl  = (lo >> 16) & 127;
        int src = lo & 0xFFFFu;
        float wm = __uint_as_float((unsigned int)(ent >> 32));
        int slot = atomicAdd(&ncnt[nl], 1);
        unsigned short wh = __half_as_ushort(__float2half_rn(wm));
        csr[lb[nl] + slot] = (unsigned int)src | ((unsigned int)wh << 16);
    }
}

__device__ inline float hdec(unsigned int u) {
    return __half2float(__ushort_as_half((unsigned short)(u >> 16)));
}

// == gather (512 thr, R3-verbatim): WIDE 16B/lane table reads (123->38us
// measured). cq=ln&3 picks a float4 (8 halves) of the 64B row; sg=ln>>2
// picks the edge -> 8 edges per load step, 4 lane-addresses/edge.
// BN stats: block LDS reduce -> atomics spread over NCOPY copies
// (R1 lesson: 128 addresses x 3125 serialized adds = +70us/launch).
// out[d] = dd * ( sum_e wm_e * h'[s_e] + h'[d] ) + bias   (h' = dinv*h)
__global__ __launch_bounds__(512) void k_gather(const __half* __restrict__ ha,
                                                const __half* __restrict__ hb,
                                                const unsigned int* __restrict__ csr,
                                                const int2*  __restrict__ row_se,
                                                const float* __restrict__ dinv,
                                                const float* __restrict__ bias,
                                                float* __restrict__ out,
                                                float* __restrict__ stat) {
    __shared__ float s1[512], s2[512];
    int t = threadIdx.x;
    int half = blockIdx.x & 1;
    const float4* __restrict__ h4 = (const float4*)(half ? hb : ha);
    int node = (blockIdx.x >> 1) * 16 + (t >> 5);
    int ln = t & 31;
    int sg = ln >> 2;     // 0..7: edge subgroup
    int cq = ln & 3;      // 0..3: column quad (8 cols = 16B)
    int2 se = row_se[node];
    float dd = dinv[node];
    float acc[8];
    if (sg == 0) {        // self term (pre-scaled by dinv), added once
        float4 sv = h4[node * 4 + cq];
        const __half2* p = reinterpret_cast<const __half2*>(&sv);
#pragma unroll
        for (int i = 0; i < 4; ++i) {
            float2 f = __half22float2(p[i]);
            acc[2 * i] = f.x; acc[2 * i + 1] = f.y;
        }
    } else {
#pragma unroll
        for (int i = 0; i < 8; ++i) acc[i] = 0.0f;
    }
    for (int b = se.x; b < se.y; b += 32) {
        int c0 = min(32, se.y - b);
        int cm = c0 - 1;
        unsigned int my = (ln < c0) ? csr[b + ln] : 0u;
        // 4 masked steps x 8 edges; clamp keeps addresses valid, w=0 kills
        // the contribution. Poisson(32) degrees => <15% wasted slots.
        unsigned int u0 = __shfl(my, min(sg,      cm), 32);
        unsigned int u1 = __shfl(my, min(sg + 8,  cm), 32);
        unsigned int u2 = __shfl(my, min(sg + 16, cm), 32);
        unsigned int u3 = __shfl(my, min(sg + 24, cm), 32);
        float4 r0 = h4[(u0 & 0xFFFFu) * 4 + cq];
        float4 r1 = h4[(u1 & 0xFFFFu) * 4 + cq];
        float4 r2 = h4[(u2 & 0xFFFFu) * 4 + cq];
        float4 r3 = h4[(u3 & 0xFFFFu) * 4 + cq];
        float w0 = (sg      < c0) ? hdec(u0) : 0.0f;
        float w1 = (sg + 8  < c0) ? hdec(u1) : 0.0f;
        float w2 = (sg + 16 < c0) ? hdec(u2) : 0.0f;
        float w3 = (sg + 24 < c0) ? hdec(u3) : 0.0f;
        const __half2* p0 = reinterpret_cast<const __half2*>(&r0);
        const __half2* p1 = reinterpret_cast<const __half2*>(&r1);
        const __half2* p2 = reinterpret_cast<const __half2*>(&r2);
        const __half2* p3 = reinterpret_cast<const __half2*>(&r3);
#pragma unroll
        for (int i = 0; i < 4; ++i) {
            float2 f0 = __half22float2(p0[i]);
            float2 f1 = __half22float2(p1[i]);
            float2 f2 = __half22float2(p2[i]);
            float2 f3 = __half22float2(p3[i]);
            acc[2*i]   = fmaf(f0.x, w0, acc[2*i]);
            acc[2*i+1] = fmaf(f0.y, w0, acc[2*i+1]);
            acc[2*i]   = fmaf(f1.x, w1, acc[2*i]);
            acc[2*i+1] = fmaf(f1.y, w1, acc[2*i+1]);
            acc[2*i]   = fmaf(f2.x, w2, acc[2*i]);
            acc[2*i+1] = fmaf(f2.y, w2, acc[2*i+1]);
            acc[2*i]   = fmaf(f3.x, w3, acc[2*i]);
            acc[2*i+1] = fmaf(f3.y, w3, acc[2*i+1]);
        }
    }
    // fold 8 edge-subgroups (stride-4 lanes) -> lanes 0..3 hold 32 cols
#pragma unroll
    for (int off = 16; off >= 4; off >>= 1) {
#pragma unroll
        for (int i = 0; i < 8; ++i) acc[i] += __shfl_down(acc[i], off, 32);
    }
    if (ln < 4) {
        int col0 = half * 32 + cq * 8;
        float v[8];
#pragma unroll
        for (int i = 0; i < 8; ++i) v[i] = fmaf(acc[i], dd, bias[col0 + i]);
        float4* o = (float4*)out;
        o[node * 16 + half * 8 + cq * 2]     = make_float4(v[0], v[1], v[2], v[3]);
        o[node * 16 + half * 8 + cq * 2 + 1] = make_float4(v[4], v[5], v[6], v[7]);
        int lb = (t >> 5) * 32 + cq * 8;
#pragma unroll
        for (int i = 0; i < 8; ++i) { s1[lb + i] = v[i]; s2[lb + i] = v[i] * v[i]; }
    }
    __syncthreads();
#pragma unroll
    for (int off = 256; off >= 32; off >>= 1) {
        if (t < off) { s1[t] += s1[t + off]; s2[t] += s2[t + off]; }
        __syncthreads();
    }
    if (t < 32) {
        int cp = (blockIdx.x >> 1) & (NCOPY - 1);
        int col = half * 32 + t;
        atomicAdd(&stat[cp * 128 + col],      s1[t]);
        atomicAdd(&stat[cp * 128 + 64 + col], s2[t]);
    }
}

// == GEMM2 fused BN1+ReLU in, dinv-scaled split fp16 out: [N,64]x[64,64] ====
// BN scale/shift computed inline from NCOPY-spread stat accumulators.
__global__ __launch_bounds__(256) void k_gemm2_bn(const float* __restrict__ hin,
                                                  const float* __restrict__ stat,
                                                  const float* __restrict__ gamma,
                                                  const float* __restrict__ beta,
                                                  const float* __restrict__ W,
                                                  const float* __restrict__ dinv,
                                                  __half* __restrict__ ha,
                                                  __half* __restrict__ hb) {
    __shared__ float sw[D_HID * D_HID];   // 16 KB
    __shared__ float sx[16 * D_HID];      // 4 KB
    __shared__ float sc[D_HID], sh[D_HID];
    int t = threadIdx.x;
    int row0 = blockIdx.x * 16;
#pragma unroll
    for (int j = 0; j < 16; ++j) sw[t + j * 256] = W[t + j * 256];
    if (t < 64) {
        float s = 0.0f, q = 0.0f;
#pragma unroll 8
        for (int c = 0; c < NCOPY; ++c) {
            s += stat[c * 128 + t];
            q += stat[c * 128 + 64 + t];
        }
        const float invn = 1.0f / (float)N_NODES;
        float mean = s * invn;
        float var  = q * invn - mean * mean;   // biased, = jnp.var
        float g    = gamma[t] * rsqrtf(var + BN_EPS);
        sc[t] = g;
        sh[t] = beta[t] - mean * g;
    }
    __syncthreads();
#pragma unroll
    for (int j = 0; j < 4; ++j) {
        int i = t + j * 256;
        int k = i & 63;
        sx[i] = fmaxf(0.0f, fmaf(hin[row0 * D_HID + i], sc[k], sh[k]));
    }
    __syncthreads();
    int c = t & 63, rg = (t >> 6) * 4;
    float a0 = 0, a1 = 0, a2 = 0, a3 = 0;
#pragma unroll 4
    for (int k = 0; k < D_HID; ++k) {
        float w = sw[k * D_HID + c];
        a0 = fmaf(sx[(rg + 0) * D_HID + k], w, a0);
        a1 = fmaf(sx[(rg + 1) * D_HID + k], w, a1);
        a2 = fmaf(sx[(rg + 2) * D_HID + k], w, a2);
        a3 = fmaf(sx[(rg + 3) * D_HID + k], w, a3);
    }
    __half* tbl = (c < 32) ? ha : hb;
    int cc = c & 31;
    tbl[(row0 + rg + 0) * 32 + cc] = __float2half_rn(a0 * dinv[row0 + rg + 0]);
    tbl[(row0 + rg + 1) * 32 + cc] = __float2half_rn(a1 * dinv[row0 + rg + 1]);
    tbl[(row0 + rg + 2) * 32 + cc] = __float2half_rn(a2 * dinv[row0 + rg + 2]);
    tbl[(row0 + rg + 3) * 32 + cc] = __float2half_rn(a3 * dinv[row0 + rg + 3]);
}

// ====== BN apply + ReLU (in place, float4); coeffs from spread stats =======
__global__ __launch_bounds__(256) void k_bn_apply_relu(float4* __restrict__ h,
                                                       const float* __restrict__ stat,
                                                       const float* __restrict__ gamma,
                                                       const float* __restrict__ beta) {
    __shared__ float sc[D_HID], sh[D_HID];
    int t = threadIdx.x;
    if (t < 64) {
        float s = 0.0f, q = 0.0f;
#pragma unroll 8
        for (int c = 0; c < NCOPY; ++c) {
            s += stat[c * 128 + t];
            q += stat[c * 128 + 64 + t];
        }
        const float invn = 1.0f / (float)N_NODES;
        float mean = s * invn;
        float var  = q * invn - mean * mean;
        float g    = gamma[t] * rsqrtf(var + BN_EPS);
        sc[t] = g;
        sh[t] = beta[t] - mean * g;
    }
    __syncthreads();
    int idx = blockIdx.x * 256 + t;
    if (idx >= N_NODES * D_HID / 4) return;
    int j = (idx & 15) * 4;
    float4 v = h[idx];
    v.x = fmaxf(0.0f, fmaf(v.x, sc[j],     sh[j]));
    v.y = fmaxf(0.0f, fmaf(v.y, sc[j + 1], sh[j + 1]));
    v.z = fmaxf(0.0f, fmaf(v.z, sc[j + 2], sh[j + 2]));
    v.w = fmaxf(0.0f, fmaf(v.w, sc[j + 3], sh[j + 3]));
    h[idx] = v;
}

extern "C" void kernel_launch(void* const* d_in, const int* in_sizes, int n_in,
                              void* d_out, int out_size, void* d_ws, size_t ws_size,
                              hipStream_t stream) {
    const float* x     = (const float*)d_in[0];
    const int*   ei_sc = (const int*)  d_in[1];   // [2*E] src then dst
    const float* w_sc  = (const float*)d_in[2];
    const float* w_fc  = (const float*)d_in[4];
    const float* alpha = (const float*)d_in[5];
    const float* W1    = (const float*)d_in[6];
    const float* b1    = (const float*)d_in[7];
    const float* W2    = (const float*)d_in[8];
    const float* b2    = (const float*)d_in[9];
    const float* g1    = (const float*)d_in[10];
    const float* be1   = (const float*)d_in[11];
    const float* g2    = (const float*)d_in[12];
    const float* be2   = (const float*)d_in[13];
    float* out = (float*)d_out;

    // ---- workspace layout, all segments 16B-aligned (R3-verbatim): ~41.5 MB
    // binned | row_se | bin_cur(400 pad) | stats | dinv | csr | ha | hb | agg
    unsigned long long* binned = (unsigned long long*)d_ws;        // NBINS*BINCAP u64
    int2*  row_se  = (int2*)(binned + (size_t)NBINS * BINCAP);     // N int2
    int*   bin_cur = (int*)(row_se + N_NODES);                     // 400 (391 used)
    float* stats   = (float*)(bin_cur + 400);                      // 2*NCOPY*128
    float* dinv    = stats + 2 * NCOPY * 128;                      // N
    unsigned int* csr = (unsigned int*)(dinv + N_NODES);           // NBINS*BINCAP
    __half* ha     = (__half*)(csr + (size_t)NBINS * BINCAP);      // N*32 halves
    __half* hb     = ha + (size_t)N_NODES * 32;                    // N*32 halves
    float* agg     = (float*)(hb + (size_t)N_NODES * 32);          // N*64

    const int gV4 = (N_NODES * D_HID / 4 + 255) / 256;             // 3125
    const int gGA = NPAIR * 2;                                     // 6250
    const int gGM = N_NODES / 16;                                  // 3125

    // ---- fused binA+gemm1, then merged CSR build (+dinv fold into h).
    // one memset covers bin_cur AND both layers' spread stat accumulators.
    hipMemsetAsync(bin_cur, 0, (400 + 2 * NCOPY * 128) * sizeof(int), stream);
    k_pre <<<256 + GEMM1B, 256, 0, stream>>>(w_sc, w_fc, ei_sc, alpha,
                                             bin_cur, binned, x, W1, ha, hb);
    k_binB<<<NBINS, 512, 0, stream>>>(bin_cur, binned, row_se, dinv, ha, hb, csr);

    // ---- layer 1 (BN stats spread-atomic accumulated in gather epilogue)
    k_gather  <<<gGA, 512, 0, stream>>>(ha, hb, csr, row_se, dinv, b1, agg, stats);

    // ---- layer 2 (BN1+ReLU coeffs computed inline; dinv folded into output)
    k_gemm2_bn<<<gGM, 256, 0, stream>>>(agg, stats, g1, be1, W2, dinv, ha, hb);
    k_gather  <<<gGA, 512, 0, stream>>>(ha, hb, csr, row_se, dinv, b2, out,
                                        stats + NCOPY * 128);
    k_bn_apply_relu<<<gV4, 256, 0, stream>>>((float4*)out, stats + NCOPY * 128,
                                             g2, be2);
}